// Round 11
// baseline (84.974 us; speedup 1.0000x reference)
//
#include <hip/hip_runtime.h>
#include <math.h>

// Cox partial likelihood NLL.
// loss = -(1/n) * sum_i e_i * (risk_i - log(P[time_i]))
//   where P[t] = sum_{t' <= t} S[t'],  S[t] = sum_{time_j = t} exp(risk_j)
// Decompose: A = sum_i e_i*risk_i ; B = sum_t E[t]*log(P[t]), E[t] = sum_{time_j=t} e_j
// loss = -(A - B)/n
//
// R11 = R10 with the compile fix: __builtin_nontemporal_load needs clang
// ext_vector_type, not HIP_vector_type. Theory unchanged: R8/R9 ablations
// showed the limiter is the line stream through the per-CU L1 path (pure-load
// probe == full kernel; L3-resident == cold; strided == coalesced). Streams
// have zero reuse; nt (no-allocate) is the remaining lever on that path.

#define TMAXV   100000
#define NPAD    100352          // 98 * 1024, padded bucket count
#define NBLK_SC 98
#define VPT     16              // elements per thread per window
#define NBLK1   2048
#define SENT    0x7fffffff      // sentinel time for invalid lanes

typedef float fx4 __attribute__((ext_vector_type(4)));
typedef int   ix4 __attribute__((ext_vector_type(4)));

__device__ __forceinline__ void atomAddF(float* p, float v) {
    unsafeAtomicAdd(p, v);      // native global_atomic_add_f32
}

// Block reduce (up to 16 waves). Result valid in lane 0 of wave 0 only.
__device__ __forceinline__ float block_reduce_sum(float v, float* lds) {
    const int lane = threadIdx.x & 63;
    const int wid  = threadIdx.x >> 6;
    #pragma unroll
    for (int d = 32; d > 0; d >>= 1) v += __shfl_down(v, d);
    __syncthreads();
    if (lane == 0) lds[wid] = v;
    __syncthreads();
    float r = 0.f;
    if (wid == 0) {
        const int nw = (int)(blockDim.x >> 6);
        r = (lane < nw) ? lds[lane] : 0.f;
        #pragma unroll
        for (int d = 8; d > 0; d >>= 1) r += __shfl_down(r, d);
    }
    return r;
}

__global__ __launch_bounds__(256)
void k1_bucket(const float* __restrict__ risk, const float* __restrict__ ev,
               const int* __restrict__ tim,
               float* __restrict__ S, float* __restrict__ E,
               float* __restrict__ Apart, int n, int per_block) {
    __shared__ float lds[16];
    const int lane  = threadIdx.x & 63;
    const int start = (int)blockIdx.x * per_block;
    int end = start + per_block;
    if (end > n) end = n;
    const int step = 256 * VPT;

    float accA = 0.f;
    for (int i0 = start; i0 < end; i0 += step) {
        const int base = i0 + (int)threadIdx.x * VPT;  // this thread's strip
        float r[VPT], w[VPT];
        int   t[VPT];
        if (base + VPT <= end) {
            #pragma unroll
            for (int q = 0; q < VPT / 4; ++q) {
                const fx4 rr = __builtin_nontemporal_load((const fx4*)(risk + base + 4 * q));
                const fx4 ww = __builtin_nontemporal_load((const fx4*)(ev   + base + 4 * q));
                const ix4 tt = __builtin_nontemporal_load((const ix4*)(tim  + base + 4 * q));
                #pragma unroll
                for (int j = 0; j < 4; ++j) {
                    r[4*q+j] = rr[j];
                    w[4*q+j] = ww[j];
                    t[4*q+j] = tt[j];
                }
            }
        } else {
            #pragma unroll
            for (int j = 0; j < VPT; ++j) {
                const int i = base + j;
                const bool ok = (i < end);
                r[j] = ok ? risk[i] : 0.f;
                w[j] = ok ? ev[i]   : 0.f;
                t[j] = ok ? tim[i]  : SENT;
            }
        }

        float ve[VPT];
        #pragma unroll
        for (int j = 0; j < VPT; ++j) {
            ve[j] = __expf(r[j]);
            accA += w[j] * r[j];          // w==0 for invalid lanes
        }

        // trailing-run sums (times sorted => equality to tail is contiguous)
        const int head_t = t[0];
        const int tail_t = t[VPT - 1];
        float tsv = 0.f, tsw = 0.f;
        #pragma unroll
        for (int j = 0; j < VPT; ++j) {
            if (t[j] == tail_t) { tsv += ve[j]; tsw += w[j]; }
        }

        // cross-lane segmented inclusive scan of trailing sums, keyed on tail_t
        float Sv = tsv, Sw = tsw;
        #pragma unroll
        for (int d = 1; d < 64; d <<= 1) {
            const float ov = __shfl_up(Sv, d);
            const float ow = __shfl_up(Sw, d);
            const int   ok = __shfl_up(tail_t, d);
            if (lane >= d && ok == tail_t) { Sv += ov; Sw += ow; }
        }

        // carry into this thread's head run (exact under sortedness)
        float cv = 0.f, cw = 0.f;
        {
            const float pv = __shfl_up(Sv, 1);
            const float pw = __shfl_up(Sw, 1);
            const int   pk = __shfl_up(tail_t, 1);
            if (lane > 0 && pk == head_t) { cv = pv; cw = pw; }
        }

        // per-thread sequential run pass, flushing closed runs
        int   cur_t = head_t;
        float cur_v = cv, cur_w = cw;
        #pragma unroll
        for (int j = 0; j < VPT; ++j) {
            if (t[j] != cur_t) {
                if (cur_t != SENT) {
                    atomAddF(&S[cur_t], cur_v);
                    atomAddF(&E[cur_t], cur_w);
                }
                cur_t = t[j]; cur_v = 0.f; cur_w = 0.f;
            }
            cur_v += ve[j]; cur_w += w[j];
        }
        // trailing run: flush only if it does not continue into the next lane
        const int nh = __shfl_down(head_t, 1);
        if ((lane == 63 || nh != tail_t) && cur_t != SENT) {
            atomAddF(&S[cur_t], cur_v);
            atomAddF(&E[cur_t], cur_w);
        }
    }

    const float tot = block_reduce_sum(accA, lds);
    if (threadIdx.x == 0) Apart[blockIdx.x] = tot;   // plain store, no hot line
}

// K2: per-1024-chunk partial sums of S.
__global__ __launch_bounds__(256)
void k2_partials(const float* __restrict__ S, float* __restrict__ partials) {
    __shared__ float lds[16];
    const int base = (int)blockIdx.x * 1024;
    float v = 0.f;
    for (int j = (int)threadIdx.x; j < 1024; j += 256) v += S[base + j];
    const float tot = block_reduce_sum(v, lds);
    if (threadIdx.x == 0) partials[blockIdx.x] = tot;
}

// K3: per-chunk inclusive scan of S (+offset), dot with E via log(P) -> B.
__global__ __launch_bounds__(1024)
void k3_scan_dot(const float* __restrict__ S, const float* __restrict__ E,
                 const float* __restrict__ partials, float* __restrict__ Bacc) {
    __shared__ float lds[16];
    __shared__ float wsum[16];
    __shared__ float s_off;
    const int tid  = (int)threadIdx.x;
    const int lane = tid & 63;
    const int wid  = tid >> 6;
    const int base = (int)blockIdx.x * 1024;

    float p = (tid < (int)blockIdx.x) ? partials[tid] : 0.f;
    const float off = block_reduce_sum(p, lds);
    if (tid == 0) s_off = off;
    __syncthreads();
    const float offset = s_off;

    const float x = S[base + tid];
    float s = x;
    #pragma unroll
    for (int d = 1; d < 64; d <<= 1) {
        const float o = __shfl_up(s, d);
        if (lane >= d) s += o;
    }
    if (lane == 63) wsum[wid] = s;
    __syncthreads();
    if (wid == 0) {
        float ws = (lane < 16) ? wsum[lane] : 0.f;
        #pragma unroll
        for (int d = 1; d < 16; d <<= 1) {
            const float o = __shfl_up(ws, d);
            if (lane >= d) ws += o;
        }
        if (lane < 16) wsum[lane] = ws;
    }
    __syncthreads();
    const float incl = s + (wid > 0 ? wsum[wid - 1] : 0.f);
    const float P = offset + incl;

    const float w = E[base + tid];
    const float c = (w != 0.f) ? w * __logf(P) : 0.f;
    const float tot = block_reduce_sum(c, lds);
    if (tid == 0) atomAddF(Bacc, tot);
}

// K4: reduce Apart[NBLK1], combine with B, write loss.
__global__ __launch_bounds__(256)
void k4_final(const float* __restrict__ Apart, const float* __restrict__ B,
              float* __restrict__ out, float inv_n) {
    __shared__ float lds[16];
    float v = 0.f;
    for (int j = (int)threadIdx.x; j < NBLK1; j += 256) v += Apart[j];
    const float tot = block_reduce_sum(v, lds);
    if (threadIdx.x == 0) out[0] = -(tot - B[0]) * inv_n;
}

extern "C" void kernel_launch(void* const* d_in, const int* in_sizes, int n_in,
                              void* d_out, int out_size, void* d_ws, size_t ws_size,
                              hipStream_t stream) {
    const float* risk = (const float*)d_in[0];
    const float* ev   = (const float*)d_in[1];
    const int*   tim  = (const int*)d_in[2];
    float* out = (float*)d_out;
    const int n = in_sizes[0];

    // ws (floats): S[NPAD] E[NPAD] partials[128] Apart[NBLK1] B[2]
    float* S        = (float*)d_ws;
    float* E        = S + NPAD;
    float* partials = E + NPAD;
    float* Apart    = partials + 128;
    float* B        = Apart + NBLK1;

    (void)hipMemsetAsync(d_ws, 0, (size_t)(2 * NPAD + 128 + NBLK1 + 2) * sizeof(float), stream);

    const int threads = 256;
    const int win = threads * VPT;                     // 4096 elements per block-iter
    int per_block = (n + NBLK1 - 1) / NBLK1;
    per_block = ((per_block + win - 1) / win) * win;   // window-aligned (8192 for N=16.7M)

    hipLaunchKernelGGL(k1_bucket, dim3(NBLK1), dim3(threads), 0, stream,
                       risk, ev, tim, S, E, Apart, n, per_block);
    hipLaunchKernelGGL(k2_partials, dim3(NBLK_SC), dim3(256), 0, stream, S, partials);
    hipLaunchKernelGGL(k3_scan_dot, dim3(NBLK_SC), dim3(1024), 0, stream, S, E, partials, B);
    hipLaunchKernelGGL(k4_final, dim3(1), dim3(256), 0, stream, Apart, B, out, 1.0f / (float)n);
}

// Round 12
// 54.807 us; speedup vs baseline: 1.5504x; 1.5504x over previous
//
#include <hip/hip_runtime.h>
#include <math.h>

// Cox partial likelihood NLL.
// loss = -(1/n) * sum_i e_i * (risk_i - log(P[time_i]))
//   where P[t] = sum_{t' <= t} S[t'],  S[t] = sum_{time_j = t} exp(risk_j)
// Decompose: A = sum_i e_i*risk_i ; B = sum_t E[t]*log(P[t]), E[t] = sum_{time_j=t} e_j
// loss = -(A - B)/n
//
// R12: R5's K1 verbatim (best timed; NT reverted -- R11 showed nt bypasses
// L3 and regresses warm replays 55->85us). Tail shrunk: K2 also reduces
// Apart->A (extra block, plain store); K3 finishes the loss via the
// last-block-done pattern (atomic B + threadfence + done counter), killing
// the K4 dispatch. 4 dispatches total. K1-warm is ~80-85% of the 6.3 TB/s
// ceiling for its mandatory 192 MB -> remaining cost is fixed overhead.

#define TMAXV   100000
#define NPAD    100352          // 98 * 1024, padded bucket count
#define NBLK_SC 98
#define VPT     16              // elements per thread per window
#define NBLK1   2048
#define SENT    0x7fffffff      // sentinel time for invalid lanes

__device__ __forceinline__ void atomAddF(float* p, float v) {
    unsafeAtomicAdd(p, v);      // native global_atomic_add_f32
}

// Block reduce (up to 16 waves). Result valid in lane 0 of wave 0 only.
__device__ __forceinline__ float block_reduce_sum(float v, float* lds) {
    const int lane = threadIdx.x & 63;
    const int wid  = threadIdx.x >> 6;
    #pragma unroll
    for (int d = 32; d > 0; d >>= 1) v += __shfl_down(v, d);
    __syncthreads();
    if (lane == 0) lds[wid] = v;
    __syncthreads();
    float r = 0.f;
    if (wid == 0) {
        const int nw = (int)(blockDim.x >> 6);
        r = (lane < nw) ? lds[lane] : 0.f;
        #pragma unroll
        for (int d = 8; d > 0; d >>= 1) r += __shfl_down(r, d);
    }
    return r;
}

__global__ __launch_bounds__(256)
void k1_bucket(const float* __restrict__ risk, const float* __restrict__ ev,
               const int* __restrict__ tim,
               float* __restrict__ S, float* __restrict__ E,
               float* __restrict__ Apart, int n, int per_block) {
    __shared__ float lds[16];
    const int lane  = threadIdx.x & 63;
    const int start = (int)blockIdx.x * per_block;
    int end = start + per_block;
    if (end > n) end = n;
    const int step = 256 * VPT;

    float accA = 0.f;
    for (int i0 = start; i0 < end; i0 += step) {
        const int base = i0 + (int)threadIdx.x * VPT;  // this thread's strip
        float r[VPT], w[VPT];
        int   t[VPT];
        if (base + VPT <= end) {
            #pragma unroll
            for (int q = 0; q < VPT / 4; ++q) {
                const float4 rr = *(const float4*)(risk + base + 4 * q);
                const float4 ww = *(const float4*)(ev   + base + 4 * q);
                const int4   tt = *(const int4*)(tim   + base + 4 * q);
                r[4*q+0]=rr.x; r[4*q+1]=rr.y; r[4*q+2]=rr.z; r[4*q+3]=rr.w;
                w[4*q+0]=ww.x; w[4*q+1]=ww.y; w[4*q+2]=ww.z; w[4*q+3]=ww.w;
                t[4*q+0]=tt.x; t[4*q+1]=tt.y; t[4*q+2]=tt.z; t[4*q+3]=tt.w;
            }
        } else {
            #pragma unroll
            for (int j = 0; j < VPT; ++j) {
                const int i = base + j;
                const bool ok = (i < end);
                r[j] = ok ? risk[i] : 0.f;
                w[j] = ok ? ev[i]   : 0.f;
                t[j] = ok ? tim[i]  : SENT;
            }
        }

        float ve[VPT];
        #pragma unroll
        for (int j = 0; j < VPT; ++j) {
            ve[j] = __expf(r[j]);
            accA += w[j] * r[j];          // w==0 for invalid lanes
        }

        // trailing-run sums (times sorted => equality to tail is contiguous)
        const int head_t = t[0];
        const int tail_t = t[VPT - 1];
        float tsv = 0.f, tsw = 0.f;
        #pragma unroll
        for (int j = 0; j < VPT; ++j) {
            if (t[j] == tail_t) { tsv += ve[j]; tsw += w[j]; }
        }

        // cross-lane segmented inclusive scan of trailing sums, keyed on tail_t
        float Sv = tsv, Sw = tsw;
        #pragma unroll
        for (int d = 1; d < 64; d <<= 1) {
            const float ov = __shfl_up(Sv, d);
            const float ow = __shfl_up(Sw, d);
            const int   ok = __shfl_up(tail_t, d);
            if (lane >= d && ok == tail_t) { Sv += ov; Sw += ow; }
        }

        // carry into this thread's head run (exact under sortedness)
        float cv = 0.f, cw = 0.f;
        {
            const float pv = __shfl_up(Sv, 1);
            const float pw = __shfl_up(Sw, 1);
            const int   pk = __shfl_up(tail_t, 1);
            if (lane > 0 && pk == head_t) { cv = pv; cw = pw; }
        }

        // per-thread sequential run pass, flushing closed runs
        int   cur_t = head_t;
        float cur_v = cv, cur_w = cw;
        #pragma unroll
        for (int j = 0; j < VPT; ++j) {
            if (t[j] != cur_t) {
                if (cur_t != SENT) {
                    atomAddF(&S[cur_t], cur_v);
                    atomAddF(&E[cur_t], cur_w);
                }
                cur_t = t[j]; cur_v = 0.f; cur_w = 0.f;
            }
            cur_v += ve[j]; cur_w += w[j];
        }
        // trailing run: flush only if it does not continue into the next lane
        const int nh = __shfl_down(head_t, 1);
        if ((lane == 63 || nh != tail_t) && cur_t != SENT) {
            atomAddF(&S[cur_t], cur_v);
            atomAddF(&E[cur_t], cur_w);
        }
    }

    const float tot = block_reduce_sum(accA, lds);
    if (threadIdx.x == 0) Apart[blockIdx.x] = tot;   // plain store, no hot line
}

// K2: blocks 0..97 compute per-1024-chunk partial sums of S;
//     block 98 reduces Apart[NBLK1] -> A (plain store, single writer).
__global__ __launch_bounds__(256)
void k2_partials(const float* __restrict__ S, float* __restrict__ partials,
                 const float* __restrict__ Apart, float* __restrict__ A) {
    __shared__ float lds[16];
    if ((int)blockIdx.x == NBLK_SC) {
        float v = 0.f;
        for (int j = (int)threadIdx.x; j < NBLK1; j += 256) v += Apart[j];
        const float tot = block_reduce_sum(v, lds);
        if (threadIdx.x == 0) A[0] = tot;
        return;
    }
    const int base = (int)blockIdx.x * 1024;
    float v = 0.f;
    for (int j = (int)threadIdx.x; j < 1024; j += 256) v += S[base + j];
    const float tot = block_reduce_sum(v, lds);
    if (threadIdx.x == 0) partials[blockIdx.x] = tot;
}

// K3: per-chunk inclusive scan of S (+offset), dot with E via log(P) -> B;
//     last block to finish combines with A and writes the loss (no K4).
__global__ __launch_bounds__(1024)
void k3_scan_dot(const float* __restrict__ S, const float* __restrict__ E,
                 const float* __restrict__ partials, float* __restrict__ Bacc,
                 int* __restrict__ done, const float* __restrict__ A,
                 float* __restrict__ out, float inv_n) {
    __shared__ float lds[16];
    __shared__ float wsum[16];
    __shared__ float s_off;
    const int tid  = (int)threadIdx.x;
    const int lane = tid & 63;
    const int wid  = tid >> 6;
    const int base = (int)blockIdx.x * 1024;

    float p = (tid < (int)blockIdx.x) ? partials[tid] : 0.f;
    const float off = block_reduce_sum(p, lds);
    if (tid == 0) s_off = off;
    __syncthreads();
    const float offset = s_off;

    const float x = S[base + tid];
    float s = x;
    #pragma unroll
    for (int d = 1; d < 64; d <<= 1) {
        const float o = __shfl_up(s, d);
        if (lane >= d) s += o;
    }
    if (lane == 63) wsum[wid] = s;
    __syncthreads();
    if (wid == 0) {
        float ws = (lane < 16) ? wsum[lane] : 0.f;
        #pragma unroll
        for (int d = 1; d < 16; d <<= 1) {
            const float o = __shfl_up(ws, d);
            if (lane >= d) ws += o;
        }
        if (lane < 16) wsum[lane] = ws;
    }
    __syncthreads();
    const float incl = s + (wid > 0 ? wsum[wid - 1] : 0.f);
    const float P = offset + incl;

    const float w = E[base + tid];
    const float c = (w != 0.f) ? w * __logf(P) : 0.f;
    const float tot = block_reduce_sum(c, lds);

    if (tid == 0) {
        atomAddF(Bacc, tot);
        __threadfence();                          // make B add visible
        const int old = atomicAdd(done, 1);       // device-scope int atomic
        if (old == NBLK_SC - 1) {                 // last block finishes
            __threadfence();
            out[0] = -(A[0] - *(volatile float*)Bacc) * inv_n;
        }
    }
}

extern "C" void kernel_launch(void* const* d_in, const int* in_sizes, int n_in,
                              void* d_out, int out_size, void* d_ws, size_t ws_size,
                              hipStream_t stream) {
    const float* risk = (const float*)d_in[0];
    const float* ev   = (const float*)d_in[1];
    const int*   tim  = (const int*)d_in[2];
    float* out = (float*)d_out;
    const int n = in_sizes[0];

    // ws (floats): S[NPAD] | E[NPAD] | B | done | A | pad | partials[128] | Apart[NBLK1]
    float* S        = (float*)d_ws;
    float* E        = S + NPAD;
    float* B        = E + NPAD;
    int*   done     = (int*)(B + 1);
    float* A        = B + 2;
    float* partials = B + 4;
    float* Apart    = partials + 128;

    // zero S, E, B, done (A/partials/Apart are fully rewritten every call)
    (void)hipMemsetAsync(d_ws, 0, (size_t)(2 * NPAD + 2) * sizeof(float), stream);

    const int threads = 256;
    const int win = threads * VPT;                     // 4096 elements per block-iter
    int per_block = (n + NBLK1 - 1) / NBLK1;
    per_block = ((per_block + win - 1) / win) * win;   // window-aligned (8192 for N=16.7M)

    hipLaunchKernelGGL(k1_bucket, dim3(NBLK1), dim3(threads), 0, stream,
                       risk, ev, tim, S, E, Apart, n, per_block);
    hipLaunchKernelGGL(k2_partials, dim3(NBLK_SC + 1), dim3(256), 0, stream,
                       S, partials, Apart, A);
    hipLaunchKernelGGL(k3_scan_dot, dim3(NBLK_SC), dim3(1024), 0, stream,
                       S, E, partials, B, done, A, out, 1.0f / (float)n);
}

// Round 13
// 53.856 us; speedup vs baseline: 1.5778x; 1.0176x over previous
//
#include <hip/hip_runtime.h>
#include <math.h>

// Cox partial likelihood NLL.
// loss = -(1/n) * sum_i e_i * (risk_i - log(P[time_i]))
//   where P[t] = sum_{t' <= t} S[t'],  S[t] = sum_{time_j = t} exp(risk_j)
// Decompose: A = sum_i e_i*risk_i ; B = sum_t E[t]*log(P[t]), E[t] = sum_{time_j=t} e_j
// loss = -(A - B)/n
//
// R13: block-dispatch-ramp theory. R4 (8192 blocks) = 119us ~= 8192x14.5ns;
// R5/R12 (2048 blocks) K1 ~= 70us ~= 30us ramp + 40us work. Halve the ramp:
// 1024 blocks x 512 threads (same 8192 waves, same VPT=16, same 2
// window-iters/thread, same R5 inner logic, ~48 VGPR -> 100% occupancy).
// Tail stays R12-fused (K2+A-reduce, K3 writes loss via done-counter).

#define TMAXV   100000
#define NPAD    100352          // 98 * 1024, padded bucket count
#define NBLK_SC 98
#define VPT     16              // elements per thread per window
#define NBLK1   1024            // k1 grid
#define NTHR1   512             // k1 block size
#define SENT    0x7fffffff      // sentinel time for invalid lanes

__device__ __forceinline__ void atomAddF(float* p, float v) {
    unsafeAtomicAdd(p, v);      // native global_atomic_add_f32
}

// Block reduce (up to 16 waves). Result valid in lane 0 of wave 0 only.
__device__ __forceinline__ float block_reduce_sum(float v, float* lds) {
    const int lane = threadIdx.x & 63;
    const int wid  = threadIdx.x >> 6;
    #pragma unroll
    for (int d = 32; d > 0; d >>= 1) v += __shfl_down(v, d);
    __syncthreads();
    if (lane == 0) lds[wid] = v;
    __syncthreads();
    float r = 0.f;
    if (wid == 0) {
        const int nw = (int)(blockDim.x >> 6);
        r = (lane < nw) ? lds[lane] : 0.f;
        #pragma unroll
        for (int d = 8; d > 0; d >>= 1) r += __shfl_down(r, d);
    }
    return r;
}

__global__ __launch_bounds__(NTHR1)
void k1_bucket(const float* __restrict__ risk, const float* __restrict__ ev,
               const int* __restrict__ tim,
               float* __restrict__ S, float* __restrict__ E,
               float* __restrict__ Apart, int n, int per_block) {
    __shared__ float lds[16];
    const int lane  = threadIdx.x & 63;
    const int start = (int)blockIdx.x * per_block;
    int end = start + per_block;
    if (end > n) end = n;
    const int step = NTHR1 * VPT;

    float accA = 0.f;
    for (int i0 = start; i0 < end; i0 += step) {
        const int base = i0 + (int)threadIdx.x * VPT;  // this thread's strip
        float r[VPT], w[VPT];
        int   t[VPT];
        if (base + VPT <= end) {
            #pragma unroll
            for (int q = 0; q < VPT / 4; ++q) {
                const float4 rr = *(const float4*)(risk + base + 4 * q);
                const float4 ww = *(const float4*)(ev   + base + 4 * q);
                const int4   tt = *(const int4*)(tim   + base + 4 * q);
                r[4*q+0]=rr.x; r[4*q+1]=rr.y; r[4*q+2]=rr.z; r[4*q+3]=rr.w;
                w[4*q+0]=ww.x; w[4*q+1]=ww.y; w[4*q+2]=ww.z; w[4*q+3]=ww.w;
                t[4*q+0]=tt.x; t[4*q+1]=tt.y; t[4*q+2]=tt.z; t[4*q+3]=tt.w;
            }
        } else {
            #pragma unroll
            for (int j = 0; j < VPT; ++j) {
                const int i = base + j;
                const bool ok = (i < end);
                r[j] = ok ? risk[i] : 0.f;
                w[j] = ok ? ev[i]   : 0.f;
                t[j] = ok ? tim[i]  : SENT;
            }
        }

        float ve[VPT];
        #pragma unroll
        for (int j = 0; j < VPT; ++j) {
            ve[j] = __expf(r[j]);
            accA += w[j] * r[j];          // w==0 for invalid lanes
        }

        // trailing-run sums (times sorted => equality to tail is contiguous)
        const int head_t = t[0];
        const int tail_t = t[VPT - 1];
        float tsv = 0.f, tsw = 0.f;
        #pragma unroll
        for (int j = 0; j < VPT; ++j) {
            if (t[j] == tail_t) { tsv += ve[j]; tsw += w[j]; }
        }

        // cross-lane segmented inclusive scan of trailing sums, keyed on tail_t
        float Sv = tsv, Sw = tsw;
        #pragma unroll
        for (int d = 1; d < 64; d <<= 1) {
            const float ov = __shfl_up(Sv, d);
            const float ow = __shfl_up(Sw, d);
            const int   ok = __shfl_up(tail_t, d);
            if (lane >= d && ok == tail_t) { Sv += ov; Sw += ow; }
        }

        // carry into this thread's head run (exact under sortedness)
        float cv = 0.f, cw = 0.f;
        {
            const float pv = __shfl_up(Sv, 1);
            const float pw = __shfl_up(Sw, 1);
            const int   pk = __shfl_up(tail_t, 1);
            if (lane > 0 && pk == head_t) { cv = pv; cw = pw; }
        }

        // per-thread sequential run pass, flushing closed runs
        int   cur_t = head_t;
        float cur_v = cv, cur_w = cw;
        #pragma unroll
        for (int j = 0; j < VPT; ++j) {
            if (t[j] != cur_t) {
                if (cur_t != SENT) {
                    atomAddF(&S[cur_t], cur_v);
                    atomAddF(&E[cur_t], cur_w);
                }
                cur_t = t[j]; cur_v = 0.f; cur_w = 0.f;
            }
            cur_v += ve[j]; cur_w += w[j];
        }
        // trailing run: flush only if it does not continue into the next lane
        const int nh = __shfl_down(head_t, 1);
        if ((lane == 63 || nh != tail_t) && cur_t != SENT) {
            atomAddF(&S[cur_t], cur_v);
            atomAddF(&E[cur_t], cur_w);
        }
    }

    const float tot = block_reduce_sum(accA, lds);
    if (threadIdx.x == 0) Apart[blockIdx.x] = tot;   // plain store, no hot line
}

// K2: blocks 0..97 compute per-1024-chunk partial sums of S;
//     block 98 reduces Apart[NBLK1] -> A (plain store, single writer).
__global__ __launch_bounds__(256)
void k2_partials(const float* __restrict__ S, float* __restrict__ partials,
                 const float* __restrict__ Apart, float* __restrict__ A) {
    __shared__ float lds[16];
    if ((int)blockIdx.x == NBLK_SC) {
        float v = 0.f;
        for (int j = (int)threadIdx.x; j < NBLK1; j += 256) v += Apart[j];
        const float tot = block_reduce_sum(v, lds);
        if (threadIdx.x == 0) A[0] = tot;
        return;
    }
    const int base = (int)blockIdx.x * 1024;
    float v = 0.f;
    for (int j = (int)threadIdx.x; j < 1024; j += 256) v += S[base + j];
    const float tot = block_reduce_sum(v, lds);
    if (threadIdx.x == 0) partials[blockIdx.x] = tot;
}

// K3: per-chunk inclusive scan of S (+offset), dot with E via log(P) -> B;
//     last block to finish combines with A and writes the loss (no K4).
__global__ __launch_bounds__(1024)
void k3_scan_dot(const float* __restrict__ S, const float* __restrict__ E,
                 const float* __restrict__ partials, float* __restrict__ Bacc,
                 int* __restrict__ done, const float* __restrict__ A,
                 float* __restrict__ out, float inv_n) {
    __shared__ float lds[16];
    __shared__ float wsum[16];
    __shared__ float s_off;
    const int tid  = (int)threadIdx.x;
    const int lane = tid & 63;
    const int wid  = tid >> 6;
    const int base = (int)blockIdx.x * 1024;

    float p = (tid < (int)blockIdx.x) ? partials[tid] : 0.f;
    const float off = block_reduce_sum(p, lds);
    if (tid == 0) s_off = off;
    __syncthreads();
    const float offset = s_off;

    const float x = S[base + tid];
    float s = x;
    #pragma unroll
    for (int d = 1; d < 64; d <<= 1) {
        const float o = __shfl_up(s, d);
        if (lane >= d) s += o;
    }
    if (lane == 63) wsum[wid] = s;
    __syncthreads();
    if (wid == 0) {
        float ws = (lane < 16) ? wsum[lane] : 0.f;
        #pragma unroll
        for (int d = 1; d < 16; d <<= 1) {
            const float o = __shfl_up(ws, d);
            if (lane >= d) ws += o;
        }
        if (lane < 16) wsum[lane] = ws;
    }
    __syncthreads();
    const float incl = s + (wid > 0 ? wsum[wid - 1] : 0.f);
    const float P = offset + incl;

    const float w = E[base + tid];
    const float c = (w != 0.f) ? w * __logf(P) : 0.f;
    const float tot = block_reduce_sum(c, lds);

    if (tid == 0) {
        atomAddF(Bacc, tot);
        __threadfence();                          // make B add visible
        const int old = atomicAdd(done, 1);       // device-scope int atomic
        if (old == NBLK_SC - 1) {                 // last block finishes
            __threadfence();
            out[0] = -(A[0] - *(volatile float*)Bacc) * inv_n;
        }
    }
}

extern "C" void kernel_launch(void* const* d_in, const int* in_sizes, int n_in,
                              void* d_out, int out_size, void* d_ws, size_t ws_size,
                              hipStream_t stream) {
    const float* risk = (const float*)d_in[0];
    const float* ev   = (const float*)d_in[1];
    const int*   tim  = (const int*)d_in[2];
    float* out = (float*)d_out;
    const int n = in_sizes[0];

    // ws (floats): S[NPAD] | E[NPAD] | B | done | A | pad | partials[128] | Apart[NBLK1]
    float* S        = (float*)d_ws;
    float* E        = S + NPAD;
    float* B        = E + NPAD;
    int*   done     = (int*)(B + 1);
    float* A        = B + 2;
    float* partials = B + 4;
    float* Apart    = partials + 128;

    // zero S, E, B, done (A/partials/Apart are fully rewritten every call)
    (void)hipMemsetAsync(d_ws, 0, (size_t)(2 * NPAD + 2) * sizeof(float), stream);

    const int win = NTHR1 * VPT;                       // 8192 elements per block-iter
    int per_block = (n + NBLK1 - 1) / NBLK1;
    per_block = ((per_block + win - 1) / win) * win;   // window-aligned (16384 for N=16.7M)

    hipLaunchKernelGGL(k1_bucket, dim3(NBLK1), dim3(NTHR1), 0, stream,
                       risk, ev, tim, S, E, Apart, n, per_block);
    hipLaunchKernelGGL(k2_partials, dim3(NBLK_SC + 1), dim3(256), 0, stream,
                       S, partials, Apart, A);
    hipLaunchKernelGGL(k3_scan_dot, dim3(NBLK_SC), dim3(1024), 0, stream,
                       S, E, partials, B, done, A, out, 1.0f / (float)n);
}